// Round 11
// baseline (430.675 us; speedup 1.0000x reference)
//
#include <hip/hip_runtime.h>
#include <hip/hip_bf16.h>
#include <math.h>

typedef unsigned int uint;
typedef unsigned short ushort;
typedef unsigned char uchar;

typedef __attribute__((ext_vector_type(8))) short bf16x8;
typedef __attribute__((ext_vector_type(4))) float f32x4;
typedef __attribute__((ext_vector_type(2))) float f32x2;

#define H2S 16   // H2 row stride (floats): 64B-aligned rows, one line per gather

// ---------- small helpers ----------
__device__ __forceinline__ ushort f2bf(float f) {
    uint u = __float_as_uint(f);
    uint rounding = 0x7fffu + ((u >> 16) & 1u);   // round-to-nearest-even
    return (ushort)((u + rounding) >> 16);
}
__device__ __forceinline__ float elu(float x) {
    return x > 0.f ? x : expm1f(x);
}

// ---------- degree histogram, XCD-partitioned by dst, int4 reads ----------
__global__ __launch_bounds__(256) void count_kernel(const int* __restrict__ dst, int E,
                                                    int* __restrict__ cnt, int NN) {
    int grp = blockIdx.x & 7;
    int per = (NN + 7) >> 3;
    int lo = grp * per;
    int hi = min(NN, lo + per);
    int bid = blockIdx.x >> 3;
    int nb  = gridDim.x >> 3;
    int EV = E >> 2;
    int i = bid * blockDim.x + threadIdx.x;
    int stride = nb * blockDim.x;
    const int4* dst4 = reinterpret_cast<const int4*>(dst);
    for (; i < EV; i += stride) {
        int4 d = dst4[i];
        if (d.x >= lo && d.x < hi) atomicAdd(&cnt[d.x], 1);
        if (d.y >= lo && d.y < hi) atomicAdd(&cnt[d.y], 1);
        if (d.z >= lo && d.z < hi) atomicAdd(&cnt[d.z], 1);
        if (d.w >= lo && d.w < hi) atomicAdd(&cnt[d.w], 1);
    }
    // tail (E not multiple of 4)
    int t0 = EV * 4 + bid * blockDim.x + threadIdx.x;
    for (int j = t0; j < E; j += stride) {
        int d = dst[j];
        if (d >= lo && d < hi) atomicAdd(&cnt[d], 1);
    }
}

// ---------- single-kernel exclusive scan over cnt (one 1024-thread block) ----------
__global__ __launch_bounds__(1024) void scan_all_kernel(const int* __restrict__ cnt, int NN,
                                                        int* __restrict__ offs,
                                                        int* __restrict__ cursor,
                                                        float* __restrict__ dinv) {
    __shared__ int ts[1024];
    int t = threadIdx.x;
    int per = (NN + 1023) >> 10;
    int b0 = t * per;
    int b1 = min(NN, b0 + per);
    int s = 0;
    for (int i = b0; i < b1; ++i) s += cnt[i];
    ts[t] = s;
    __syncthreads();
    for (int d = 1; d < 1024; d <<= 1) {
        int x = (t >= d) ? ts[t - d] : 0;
        __syncthreads();
        ts[t] += x;
        __syncthreads();
    }
    int run = (t == 0) ? 0 : ts[t - 1];
    for (int i = b0; i < b1; ++i) {
        int v = cnt[i];
        offs[i]   = run;
        cursor[i] = run;
        dinv[i]   = rsqrtf((float)v + 1.0f);   // +1 self-loop
        run += v;
    }
    if (t == 1023) offs[NN] = run;   // run == E (range empty or last chunk done)
}

// ---------- bucket edges by dst, XCD-partitioned, int4 reads ----------
__global__ __launch_bounds__(256) void scatter_kernel(const int* __restrict__ src,
                                                      const int* __restrict__ dst, int E,
                                                      int* __restrict__ cursor,
                                                      int* __restrict__ ssrc, int NN) {
    int grp = blockIdx.x & 7;
    int per = (NN + 7) >> 3;
    int lo = grp * per;
    int hi = min(NN, lo + per);
    int bid = blockIdx.x >> 3;
    int nb  = gridDim.x >> 3;
    int EV = E >> 2;
    int i = bid * blockDim.x + threadIdx.x;
    int stride = nb * blockDim.x;
    const int4* dst4 = reinterpret_cast<const int4*>(dst);
    const int4* src4 = reinterpret_cast<const int4*>(src);
    for (; i < EV; i += stride) {
        int4 d = dst4[i];
        int4 s = src4[i];
        if (d.x >= lo && d.x < hi) { int p = atomicAdd(&cursor[d.x], 1); ssrc[p] = s.x; }
        if (d.y >= lo && d.y < hi) { int p = atomicAdd(&cursor[d.y], 1); ssrc[p] = s.y; }
        if (d.z >= lo && d.z < hi) { int p = atomicAdd(&cursor[d.z], 1); ssrc[p] = s.z; }
        if (d.w >= lo && d.w < hi) { int p = atomicAdd(&cursor[d.w], 1); ssrc[p] = s.w; }
    }
    int t0 = EV * 4 + bid * blockDim.x + threadIdx.x;
    for (int j = t0; j < E; j += stride) {
        int d = dst[j];
        if (d >= lo && d < hi) { int p = atomicAdd(&cursor[d], 1); ssrc[p] = src[j]; }
    }
}

// ---------- W1T(bf16)[n][k] = W1[k][n], 64x64 tiles via LDS ----------
__global__ __launch_bounds__(256) void wtrans_kernel(const float* __restrict__ W,
                                                     ushort* __restrict__ WT) {
    __shared__ float T[64][68];
    int b = blockIdx.x;                 // 0..15
    int kt = (b >> 2) * 64, nt = (b & 3) * 64;
    int t = threadIdx.x;
    int r = t >> 4, c4 = (t & 15) * 4;
    #pragma unroll
    for (int h = 0; h < 4; ++h) {
        int rr = r + h * 16;
        float4 v = *reinterpret_cast<const float4*>(&W[(size_t)(kt + rr) * 256 + nt + c4]);
        *reinterpret_cast<float4*>(&T[rr][c4]) = v;
    }
    __syncthreads();
    int nr = t >> 2, ks = (t & 3) * 16;
    uint o[8];
    #pragma unroll
    for (int i = 0; i < 16; i += 2) {
        float f0 = T[ks + i][nr];
        float f1 = T[ks + i + 1][nr];
        o[i >> 1] = (uint)f2bf(f0) | ((uint)f2bf(f1) << 16);
    }
    size_t base = (size_t)(nt + nr) * 256 + kt + ks;
    *reinterpret_cast<uint4*>(&WT[base])     = make_uint4(o[0], o[1], o[2], o[3]);
    *reinterpret_cast<uint4*>(&WT[base + 8]) = make_uint4(o[4], o[5], o[6], o[7]);
}

// ---------- GEMM1 via MFMA: H1s(fp8 e4m3)[M,256] = dinv[m] * (X @ W1) ----------
#define G1_STRIDE 40   // ushorts per LDS row (80B = 20 banks; 16B-aligned frag reads)
__global__ __launch_bounds__(256) void gemm1_mfma_kernel(const float* __restrict__ X,
                                                         const ushort* __restrict__ W1T,
                                                         const float* __restrict__ dinv,
                                                         uchar* __restrict__ H1, int M) {
    __shared__ ushort Xs[64 * G1_STRIDE];
    __shared__ ushort Ws[256 * G1_STRIDE];
    __shared__ float  Dvs[64];
    int t = threadIdx.x;
    int row0 = blockIdx.x * 64;
    int lane = t & 63;
    int w = t >> 6;
    int lr = lane & 15;     // row/col within fragment
    int lg = lane >> 4;     // k-group (8 contiguous k per lane)

    if (t < 64) {
        int grow = row0 + t;
        Dvs[t] = (grow < M) ? dinv[grow] : 0.f;
    }

    f32x4 acc[4][4];
    #pragma unroll
    for (int j = 0; j < 4; ++j)
        #pragma unroll
        for (int i = 0; i < 4; ++i)
            acc[j][i] = (f32x4){0.f, 0.f, 0.f, 0.f};

    for (int k0 = 0; k0 < 256; k0 += 32) {
        #pragma unroll
        for (int h = 0; h < 2; ++h) {
            int u = t + h * 256;
            int row = u >> 3;
            int kq = (u & 7) * 4;
            int grow = row0 + row;
            float4 v = make_float4(0.f, 0.f, 0.f, 0.f);
            if (grow < M) v = *reinterpret_cast<const float4*>(&X[(size_t)grow * 256 + k0 + kq]);
            uint lo = (uint)f2bf(v.x) | ((uint)f2bf(v.y) << 16);
            uint hi = (uint)f2bf(v.z) | ((uint)f2bf(v.w) << 16);
            *reinterpret_cast<uint2*>(&Xs[row * G1_STRIDE + kq]) = make_uint2(lo, hi);
        }
        #pragma unroll
        for (int h = 0; h < 4; ++h) {
            int u = t + h * 256;
            int n = u >> 2;
            int seg = u & 3;
            uint4 wv = *reinterpret_cast<const uint4*>(&W1T[(size_t)n * 256 + k0 + seg * 8]);
            *reinterpret_cast<uint4*>(&Ws[n * G1_STRIDE + seg * 8]) = wv;
        }
        __syncthreads();
        bf16x8 wf[4], xf[4];
        #pragma unroll
        for (int j = 0; j < 4; ++j)
            wf[j] = *reinterpret_cast<const bf16x8*>(&Ws[(w * 64 + j * 16 + lr) * G1_STRIDE + lg * 8]);
        #pragma unroll
        for (int i = 0; i < 4; ++i)
            xf[i] = *reinterpret_cast<const bf16x8*>(&Xs[(i * 16 + lr) * G1_STRIDE + lg * 8]);
        #pragma unroll
        for (int j = 0; j < 4; ++j)
            #pragma unroll
            for (int i = 0; i < 4; ++i)
                acc[j][i] = __builtin_amdgcn_mfma_f32_16x16x32_bf16(wf[j], xf[i], acc[j][i], 0, 0, 0);
        __syncthreads();
    }

    // epilogue: scale by dinv[row], pack 4 f32 -> 4 fp8 e4m3 (one dword) per lane
    #pragma unroll
    for (int mi = 0; mi < 4; ++mi) {
        int grow = row0 + mi * 16 + lr;
        float dv = Dvs[mi * 16 + lr];
        bool ok = grow < M;
        #pragma unroll
        for (int nj = 0; nj < 4; ++nj) {
            f32x4 a = acc[nj][mi];
            int pk = __builtin_amdgcn_cvt_pk_fp8_f32(a[0] * dv, a[1] * dv, 0, false);
            pk     = __builtin_amdgcn_cvt_pk_fp8_f32(a[2] * dv, a[3] * dv, pk, true);
            if (ok) {
                int col = w * 64 + nj * 16 + lg * 4;
                *reinterpret_cast<uint*>(&H1[(size_t)grow * 256 + col]) = (uint)pk;
            }
        }
    }
}

// ---------- layer-1 aggregation (+b1, ELU) fused with GEMM2 (256->10) ----------
// one wave per node: 64 lanes x 4 features. UNIFORM edge index -> scalar ssrc
// loads + SGPR-base row loads (load-bearing, see R8). Unroll 16 for MLP.
__global__ __launch_bounds__(256) void agg1_gemm2_kernel(
    const uchar* __restrict__ H1, const int* __restrict__ offs, const int* __restrict__ ssrc,
    const float* __restrict__ dinv, const float* __restrict__ b1, const float* __restrict__ W2,
    float* __restrict__ H2, int NN) {
    int lane = threadIdx.x & 63;
    int node = blockIdx.x * 4 + (threadIdx.x >> 6);
    if (node >= NN) return;
    int beg = offs[node], end = offs[node + 1];
    int col = lane * 4;
    const uchar* H1c = H1 + col;
    f32x2 accL = (f32x2){0.f, 0.f};
    f32x2 accH = (f32x2){0.f, 0.f};
    int i = beg;
    for (; i + 15 < end; i += 16) {
        uint p0, p1, p2, p3, p4, p5, p6, p7, p8, p9, pa, pb, pc, pd, pe, pf;
        {
            int s0 = ssrc[i],      s1 = ssrc[i + 1],  s2 = ssrc[i + 2],  s3 = ssrc[i + 3];
            int s4 = ssrc[i + 4],  s5 = ssrc[i + 5],  s6 = ssrc[i + 6],  s7 = ssrc[i + 7];
            int s8 = ssrc[i + 8],  s9 = ssrc[i + 9],  sa = ssrc[i + 10], sb = ssrc[i + 11];
            int sc = ssrc[i + 12], sd = ssrc[i + 13], se = ssrc[i + 14], sf = ssrc[i + 15];
            p0 = *reinterpret_cast<const uint*>(H1c + (size_t)s0 * 256);
            p1 = *reinterpret_cast<const uint*>(H1c + (size_t)s1 * 256);
            p2 = *reinterpret_cast<const uint*>(H1c + (size_t)s2 * 256);
            p3 = *reinterpret_cast<const uint*>(H1c + (size_t)s3 * 256);
            p4 = *reinterpret_cast<const uint*>(H1c + (size_t)s4 * 256);
            p5 = *reinterpret_cast<const uint*>(H1c + (size_t)s5 * 256);
            p6 = *reinterpret_cast<const uint*>(H1c + (size_t)s6 * 256);
            p7 = *reinterpret_cast<const uint*>(H1c + (size_t)s7 * 256);
            p8 = *reinterpret_cast<const uint*>(H1c + (size_t)s8 * 256);
            p9 = *reinterpret_cast<const uint*>(H1c + (size_t)s9 * 256);
            pa = *reinterpret_cast<const uint*>(H1c + (size_t)sa * 256);
            pb = *reinterpret_cast<const uint*>(H1c + (size_t)sb * 256);
            pc = *reinterpret_cast<const uint*>(H1c + (size_t)sc * 256);
            pd = *reinterpret_cast<const uint*>(H1c + (size_t)sd * 256);
            pe = *reinterpret_cast<const uint*>(H1c + (size_t)se * 256);
            pf = *reinterpret_cast<const uint*>(H1c + (size_t)sf * 256);
        }
        accL += __builtin_amdgcn_cvt_pk_f32_fp8((int)p0, false);
        accH += __builtin_amdgcn_cvt_pk_f32_fp8((int)p0, true);
        accL += __builtin_amdgcn_cvt_pk_f32_fp8((int)p1, false);
        accH += __builtin_amdgcn_cvt_pk_f32_fp8((int)p1, true);
        accL += __builtin_amdgcn_cvt_pk_f32_fp8((int)p2, false);
        accH += __builtin_amdgcn_cvt_pk_f32_fp8((int)p2, true);
        accL += __builtin_amdgcn_cvt_pk_f32_fp8((int)p3, false);
        accH += __builtin_amdgcn_cvt_pk_f32_fp8((int)p3, true);
        accL += __builtin_amdgcn_cvt_pk_f32_fp8((int)p4, false);
        accH += __builtin_amdgcn_cvt_pk_f32_fp8((int)p4, true);
        accL += __builtin_amdgcn_cvt_pk_f32_fp8((int)p5, false);
        accH += __builtin_amdgcn_cvt_pk_f32_fp8((int)p5, true);
        accL += __builtin_amdgcn_cvt_pk_f32_fp8((int)p6, false);
        accH += __builtin_amdgcn_cvt_pk_f32_fp8((int)p6, true);
        accL += __builtin_amdgcn_cvt_pk_f32_fp8((int)p7, false);
        accH += __builtin_amdgcn_cvt_pk_f32_fp8((int)p7, true);
        accL += __builtin_amdgcn_cvt_pk_f32_fp8((int)p8, false);
        accH += __builtin_amdgcn_cvt_pk_f32_fp8((int)p8, true);
        accL += __builtin_amdgcn_cvt_pk_f32_fp8((int)p9, false);
        accH += __builtin_amdgcn_cvt_pk_f32_fp8((int)p9, true);
        accL += __builtin_amdgcn_cvt_pk_f32_fp8((int)pa, false);
        accH += __builtin_amdgcn_cvt_pk_f32_fp8((int)pa, true);
        accL += __builtin_amdgcn_cvt_pk_f32_fp8((int)pb, false);
        accH += __builtin_amdgcn_cvt_pk_f32_fp8((int)pb, true);
        accL += __builtin_amdgcn_cvt_pk_f32_fp8((int)pc, false);
        accH += __builtin_amdgcn_cvt_pk_f32_fp8((int)pc, true);
        accL += __builtin_amdgcn_cvt_pk_f32_fp8((int)pd, false);
        accH += __builtin_amdgcn_cvt_pk_f32_fp8((int)pd, true);
        accL += __builtin_amdgcn_cvt_pk_f32_fp8((int)pe, false);
        accH += __builtin_amdgcn_cvt_pk_f32_fp8((int)pe, true);
        accL += __builtin_amdgcn_cvt_pk_f32_fp8((int)pf, false);
        accH += __builtin_amdgcn_cvt_pk_f32_fp8((int)pf, true);
    }
    for (; i + 3 < end; i += 4) {
        int s0 = ssrc[i], s1 = ssrc[i + 1], s2 = ssrc[i + 2], s3 = ssrc[i + 3];
        uint p0 = *reinterpret_cast<const uint*>(H1c + (size_t)s0 * 256);
        uint p1 = *reinterpret_cast<const uint*>(H1c + (size_t)s1 * 256);
        uint p2 = *reinterpret_cast<const uint*>(H1c + (size_t)s2 * 256);
        uint p3 = *reinterpret_cast<const uint*>(H1c + (size_t)s3 * 256);
        accL += __builtin_amdgcn_cvt_pk_f32_fp8((int)p0, false);
        accH += __builtin_amdgcn_cvt_pk_f32_fp8((int)p0, true);
        accL += __builtin_amdgcn_cvt_pk_f32_fp8((int)p1, false);
        accH += __builtin_amdgcn_cvt_pk_f32_fp8((int)p1, true);
        accL += __builtin_amdgcn_cvt_pk_f32_fp8((int)p2, false);
        accH += __builtin_amdgcn_cvt_pk_f32_fp8((int)p2, true);
        accL += __builtin_amdgcn_cvt_pk_f32_fp8((int)p3, false);
        accH += __builtin_amdgcn_cvt_pk_f32_fp8((int)p3, true);
    }
    for (; i < end; ++i) {
        int s = ssrc[i];
        uint p = *reinterpret_cast<const uint*>(H1c + (size_t)s * 256);
        accL += __builtin_amdgcn_cvt_pk_f32_fp8((int)p, false);
        accH += __builtin_amdgcn_cvt_pk_f32_fp8((int)p, true);
    }
    {   // self loop (row pre-scaled by dinv[node])
        uint p = *reinterpret_cast<const uint*>(H1c + (size_t)node * 256);
        accL += __builtin_amdgcn_cvt_pk_f32_fp8((int)p, false);
        accH += __builtin_amdgcn_cvt_pk_f32_fp8((int)p, true);
    }
    float dn = dinv[node];
    float a0 = elu(fmaf(accL.x, dn, b1[col + 0]));
    float a1 = elu(fmaf(accL.y, dn, b1[col + 1]));
    float a2 = elu(fmaf(accH.x, dn, b1[col + 2]));
    float a3 = elu(fmaf(accH.y, dn, b1[col + 3]));
    float hv = 0.f;
    #pragma unroll
    for (int c = 0; c < 10; ++c) {
        float p = a0 * W2[(col + 0) * 10 + c]
                + a1 * W2[(col + 1) * 10 + c]
                + a2 * W2[(col + 2) * 10 + c]
                + a3 * W2[(col + 3) * 10 + c];
        #pragma unroll
        for (int m = 1; m < 64; m <<= 1) p += __shfl_xor(p, m, 64);
        if (lane == c) hv = p;
    }
    if (lane < 10) H2[(size_t)node * H2S + lane] = dn * hv;   // fold dinv[node]
}

// ---------- layer-2 aggregation (+b2, ELU) -> per-node activations ----------
__global__ __launch_bounds__(256) void agg2_elu_kernel(
    const float* __restrict__ H2, const int* __restrict__ offs, const int* __restrict__ ssrc,
    const float* __restrict__ dinv, const float* __restrict__ b2,
    float* __restrict__ H2act, int NN) {
    int t = threadIdx.x;
    int node = blockIdx.x * 8 + (t >> 5);
    if (node >= NN) return;
    int sub = t & 31;
    int c = sub & 15;
    int e2 = sub >> 4;
    int beg = offs[node], end = offs[node + 1];
    float acc = 0.f;
    int i = beg + e2;
    for (; i + 14 < end; i += 16) {   // 8 edges per thread per iter
        int s0 = ssrc[i],      s1 = ssrc[i + 2],  s2 = ssrc[i + 4],  s3 = ssrc[i + 6];
        int s4 = ssrc[i + 8],  s5 = ssrc[i + 10], s6 = ssrc[i + 12], s7 = ssrc[i + 14];
        float h0 = H2[(size_t)s0 * H2S + c];
        float h1 = H2[(size_t)s1 * H2S + c];
        float h2 = H2[(size_t)s2 * H2S + c];
        float h3 = H2[(size_t)s3 * H2S + c];
        float h4 = H2[(size_t)s4 * H2S + c];
        float h5 = H2[(size_t)s5 * H2S + c];
        float h6 = H2[(size_t)s6 * H2S + c];
        float h7 = H2[(size_t)s7 * H2S + c];
        acc += ((h0 + h1) + (h2 + h3)) + ((h4 + h5) + (h6 + h7));
    }
    for (; i + 6 < end; i += 8) {
        int s0 = ssrc[i], s1 = ssrc[i + 2], s2 = ssrc[i + 4], s3 = ssrc[i + 6];
        float h0 = H2[(size_t)s0 * H2S + c];
        float h1 = H2[(size_t)s1 * H2S + c];
        float h2 = H2[(size_t)s2 * H2S + c];
        float h3 = H2[(size_t)s3 * H2S + c];
        acc += (h0 + h1) + (h2 + h3);
    }
    for (; i < end; i += 2) acc += H2[(size_t)ssrc[i] * H2S + c];
    if (e2 == 0) acc += H2[(size_t)node * H2S + c];   // self loop (pre-scaled)
    acc += __shfl_xor(acc, 16, 64);
    if (sub < 10) {
        float dn = dinv[node];
        H2act[(size_t)node * 10 + c] = elu(fmaf(dn, acc, b2[c]));
    }
}

// ---------- per-graph mean pool + log_softmax (binary search inline) ----------
__global__ __launch_bounds__(320) void pool_final_kernel(
    const float* __restrict__ H2act, const int* __restrict__ batch, int NN,
    float* __restrict__ out, int NG) {
    __shared__ float red[32][10];
    __shared__ float m[10];
    __shared__ float s_lse;
    int g = blockIdx.x;
    int t = threadIdx.x;
    int lo = 0, hi = NN;
    while (lo < hi) { int mid = (lo + hi) >> 1; if (batch[mid] < g) lo = mid + 1; else hi = mid; }
    int lo2 = lo, hi2 = NN;
    while (lo2 < hi2) { int mid = (lo2 + hi2) >> 1; if (batch[mid] < g + 1) lo2 = mid + 1; else hi2 = mid; }
    int grp = t / 10;
    int c = t - grp * 10;
    float acc = 0.f;
    if (grp < 32) {
        for (int n = lo + grp; n < lo2; n += 32) acc += H2act[(size_t)n * 10 + c];
        red[grp][c] = acc;
    }
    __syncthreads();
    if (t < 10) {
        float s = 0.f;
        #pragma unroll
        for (int j = 0; j < 32; ++j) s += red[j][t];
        m[t] = s / fmaxf((float)(lo2 - lo), 1.0f);
    }
    __syncthreads();
    if (t == 0) {
        float mx = -1e30f;
        for (int c2 = 0; c2 < 10; ++c2) mx = fmaxf(mx, m[c2]);
        float s = 0.f;
        for (int c2 = 0; c2 < 10; ++c2) s += expf(m[c2] - mx);
        s_lse = logf(s) + mx;
    }
    __syncthreads();
    if (t < 10) out[g * 10 + t] = m[t] - s_lse;
}

extern "C" void kernel_launch(void* const* d_in, const int* in_sizes, int n_in,
                              void* d_out, int out_size, void* d_ws, size_t ws_size,
                              hipStream_t stream) {
    const float* x     = (const float*)d_in[0];
    const int*   eidx  = (const int*)d_in[1];
    const int*   batch = (const int*)d_in[2];
    const float* W1    = (const float*)d_in[3];
    const float* b1    = (const float*)d_in[4];
    const float* W2    = (const float*)d_in[5];
    const float* b2    = (const float*)d_in[6];

    int NN = in_sizes[0] / 256;     // 50000
    int E  = in_sizes[1] / 2;       // 1600000
    int NG = out_size / 10;         // 64
    const int* src = eidx;
    const int* dst = eidx + E;

    char* ws = (char*)d_ws;
    size_t off = 0;
    auto alloc = [&](size_t bytes) -> void* {
        void* p = ws + off;
        off += (bytes + 255) & ~((size_t)255);
        return p;
    };
    int*    cnt      = (int*)alloc((size_t)NN * 4);
    int*    offs     = (int*)alloc((size_t)(NN + 1) * 4);
    int*    cursor   = (int*)alloc((size_t)NN * 4);
    float*  dinv     = (float*)alloc((size_t)NN * 4);
    ushort* W1T      = (ushort*)alloc((size_t)256 * 256 * 2);
    int*    ssrc     = (int*)alloc((size_t)E * 4);
    uchar*  H1       = (uchar*)alloc((size_t)NN * 256);
    float*  H2       = (float*)alloc((size_t)NN * H2S * 4);
    float*  H2act    = (float*)alloc((size_t)NN * 10 * 4);

    hipMemsetAsync(cnt, 0, (size_t)NN * 4, stream);

    count_kernel   <<<2048, 256, 0, stream>>>(dst, E, cnt, NN);
    scan_all_kernel<<<1, 1024, 0, stream>>>(cnt, NN, offs, cursor, dinv);
    scatter_kernel <<<2048, 256, 0, stream>>>(src, dst, E, cursor, ssrc, NN);
    wtrans_kernel  <<<16, 256, 0, stream>>>(W1, W1T);
    gemm1_mfma_kernel<<<(NN + 63) / 64, 256, 0, stream>>>(x, W1T, dinv, H1, NN);
    agg1_gemm2_kernel<<<(NN + 3) / 4, 256, 0, stream>>>(H1, offs, ssrc, dinv, b1, W2, H2, NN);
    agg2_elu_kernel  <<<(NN + 7) / 8, 256, 0, stream>>>(H2, offs, ssrc, dinv, b2, H2act, NN);
    pool_final_kernel<<<NG, 320, 0, stream>>>(H2act, batch, NN, (float*)d_out, NG);
}

// Round 12
// 305.137 us; speedup vs baseline: 1.4114x; 1.4114x over previous
//
#include <hip/hip_runtime.h>
#include <hip/hip_bf16.h>
#include <math.h>

typedef unsigned int uint;
typedef unsigned short ushort;
typedef unsigned char uchar;

typedef __attribute__((ext_vector_type(8))) short bf16x8;
typedef __attribute__((ext_vector_type(4))) float f32x4;
typedef __attribute__((ext_vector_type(2))) float f32x2;

#define H2S 16   // H2 row stride (floats): 64B-aligned rows, one line per gather

// ---------- small helpers ----------
__device__ __forceinline__ ushort f2bf(float f) {
    uint u = __float_as_uint(f);
    uint rounding = 0x7fffu + ((u >> 16) & 1u);   // round-to-nearest-even
    return (ushort)((u + rounding) >> 16);
}
__device__ __forceinline__ float elu(float x) {
    return x > 0.f ? x : expm1f(x);
}

// ---------- degree histogram, XCD-partitioned by dst, int4 reads ----------
__global__ __launch_bounds__(256) void count_kernel(const int* __restrict__ dst, int E,
                                                    int* __restrict__ cnt, int NN) {
    int grp = blockIdx.x & 7;
    int per = (NN + 7) >> 3;
    int lo = grp * per;
    int hi = min(NN, lo + per);
    int bid = blockIdx.x >> 3;
    int nb  = gridDim.x >> 3;
    int EV = E >> 2;
    int i = bid * blockDim.x + threadIdx.x;
    int stride = nb * blockDim.x;
    const int4* dst4 = reinterpret_cast<const int4*>(dst);
    for (; i < EV; i += stride) {
        int4 d = dst4[i];
        if (d.x >= lo && d.x < hi) atomicAdd(&cnt[d.x], 1);
        if (d.y >= lo && d.y < hi) atomicAdd(&cnt[d.y], 1);
        if (d.z >= lo && d.z < hi) atomicAdd(&cnt[d.z], 1);
        if (d.w >= lo && d.w < hi) atomicAdd(&cnt[d.w], 1);
    }
    int t0 = EV * 4 + bid * blockDim.x + threadIdx.x;
    for (int j = t0; j < E; j += stride) {
        int d = dst[j];
        if (d >= lo && d < hi) atomicAdd(&cnt[d], 1);
    }
}

// ---------- exclusive scan over cnt (3-phase, grid-parallel) ----------
__global__ void scan1_kernel(const int* __restrict__ cnt, int M, int* __restrict__ partials) {
    __shared__ int sh[256];
    int i = blockIdx.x * 256 + threadIdx.x;
    sh[threadIdx.x] = (i < M) ? cnt[i] : 0;
    __syncthreads();
    for (int s = 128; s > 0; s >>= 1) {
        if (threadIdx.x < s) sh[threadIdx.x] += sh[threadIdx.x + s];
        __syncthreads();
    }
    if (threadIdx.x == 0) partials[blockIdx.x] = sh[0];
}

__global__ __launch_bounds__(256) void scan2_kernel(const int* __restrict__ partials, int nb,
                                                    int* __restrict__ pscan) {
    __shared__ int tsum[256];
    int t = threadIdx.x;
    int pref[16];
    int s = 0;
    #pragma unroll
    for (int j = 0; j < 16; ++j) {
        int idx = t * 16 + j;
        int v = (idx < nb) ? partials[idx] : 0;
        pref[j] = s;
        s += v;
    }
    tsum[t] = s;
    __syncthreads();
    for (int d = 1; d < 256; d <<= 1) {
        int x = (t >= d) ? tsum[t - d] : 0;
        __syncthreads();
        tsum[t] += x;
        __syncthreads();
    }
    int base = (t == 0) ? 0 : tsum[t - 1];
    #pragma unroll
    for (int j = 0; j < 16; ++j) {
        int idx = t * 16 + j;
        if (idx < nb) pscan[idx] = base + pref[j];
    }
}

__global__ void scan3_kernel(const int* __restrict__ cnt, int M, const int* __restrict__ pscan,
                             int* __restrict__ offs, int* __restrict__ cursor,
                             float* __restrict__ dinv) {
    __shared__ int sh[256];
    int t = threadIdx.x;
    int i = blockIdx.x * 256 + t;
    int v = (i < M) ? cnt[i] : 0;
    sh[t] = v;
    __syncthreads();
    for (int d = 1; d < 256; d <<= 1) {
        int x = (t >= d) ? sh[t - d] : 0;
        __syncthreads();
        sh[t] += x;
        __syncthreads();
    }
    int incl = sh[t];
    int excl = incl - v;
    int base = pscan[blockIdx.x];
    if (i < M) {
        offs[i]   = base + excl;
        cursor[i] = base + excl;
        dinv[i]   = rsqrtf((float)v + 1.0f);   // +1 self-loop
        if (i == M - 1) offs[M] = base + incl;
    }
}

// ---------- bucket edges by dst, XCD-partitioned, int4 reads ----------
__global__ __launch_bounds__(256) void scatter_kernel(const int* __restrict__ src,
                                                      const int* __restrict__ dst, int E,
                                                      int* __restrict__ cursor,
                                                      int* __restrict__ ssrc, int NN) {
    int grp = blockIdx.x & 7;
    int per = (NN + 7) >> 3;
    int lo = grp * per;
    int hi = min(NN, lo + per);
    int bid = blockIdx.x >> 3;
    int nb  = gridDim.x >> 3;
    int EV = E >> 2;
    int i = bid * blockDim.x + threadIdx.x;
    int stride = nb * blockDim.x;
    const int4* dst4 = reinterpret_cast<const int4*>(dst);
    const int4* src4 = reinterpret_cast<const int4*>(src);
    for (; i < EV; i += stride) {
        int4 d = dst4[i];
        int4 s = src4[i];
        if (d.x >= lo && d.x < hi) { int p = atomicAdd(&cursor[d.x], 1); ssrc[p] = s.x; }
        if (d.y >= lo && d.y < hi) { int p = atomicAdd(&cursor[d.y], 1); ssrc[p] = s.y; }
        if (d.z >= lo && d.z < hi) { int p = atomicAdd(&cursor[d.z], 1); ssrc[p] = s.z; }
        if (d.w >= lo && d.w < hi) { int p = atomicAdd(&cursor[d.w], 1); ssrc[p] = s.w; }
    }
    int t0 = EV * 4 + bid * blockDim.x + threadIdx.x;
    for (int j = t0; j < E; j += stride) {
        int d = dst[j];
        if (d >= lo && d < hi) { int p = atomicAdd(&cursor[d], 1); ssrc[p] = src[j]; }
    }
}

// ---------- W1T(bf16)[n][k] = W1[k][n], 64x64 tiles via LDS ----------
__global__ __launch_bounds__(256) void wtrans_kernel(const float* __restrict__ W,
                                                     ushort* __restrict__ WT) {
    __shared__ float T[64][68];
    int b = blockIdx.x;                 // 0..15
    int kt = (b >> 2) * 64, nt = (b & 3) * 64;
    int t = threadIdx.x;
    int r = t >> 4, c4 = (t & 15) * 4;
    #pragma unroll
    for (int h = 0; h < 4; ++h) {
        int rr = r + h * 16;
        float4 v = *reinterpret_cast<const float4*>(&W[(size_t)(kt + rr) * 256 + nt + c4]);
        *reinterpret_cast<float4*>(&T[rr][c4]) = v;
    }
    __syncthreads();
    int nr = t >> 2, ks = (t & 3) * 16;
    uint o[8];
    #pragma unroll
    for (int i = 0; i < 16; i += 2) {
        float f0 = T[ks + i][nr];
        float f1 = T[ks + i + 1][nr];
        o[i >> 1] = (uint)f2bf(f0) | ((uint)f2bf(f1) << 16);
    }
    size_t base = (size_t)(nt + nr) * 256 + kt + ks;
    *reinterpret_cast<uint4*>(&WT[base])     = make_uint4(o[0], o[1], o[2], o[3]);
    *reinterpret_cast<uint4*>(&WT[base + 8]) = make_uint4(o[4], o[5], o[6], o[7]);
}

// ---------- GEMM1 via MFMA: H1s(fp8 e4m3)[M,256] = dinv[m] * (X @ W1) ----------
#define G1_STRIDE 40   // ushorts per LDS row (80B = 20 banks; 16B-aligned frag reads)
__global__ __launch_bounds__(256) void gemm1_mfma_kernel(const float* __restrict__ X,
                                                         const ushort* __restrict__ W1T,
                                                         const float* __restrict__ dinv,
                                                         uchar* __restrict__ H1, int M) {
    __shared__ ushort Xs[64 * G1_STRIDE];
    __shared__ ushort Ws[256 * G1_STRIDE];
    __shared__ float  Dvs[64];
    int t = threadIdx.x;
    int row0 = blockIdx.x * 64;
    int lane = t & 63;
    int w = t >> 6;
    int lr = lane & 15;     // row/col within fragment
    int lg = lane >> 4;     // k-group (8 contiguous k per lane)

    if (t < 64) {
        int grow = row0 + t;
        Dvs[t] = (grow < M) ? dinv[grow] : 0.f;
    }

    f32x4 acc[4][4];
    #pragma unroll
    for (int j = 0; j < 4; ++j)
        #pragma unroll
        for (int i = 0; i < 4; ++i)
            acc[j][i] = (f32x4){0.f, 0.f, 0.f, 0.f};

    for (int k0 = 0; k0 < 256; k0 += 32) {
        #pragma unroll
        for (int h = 0; h < 2; ++h) {
            int u = t + h * 256;
            int row = u >> 3;
            int kq = (u & 7) * 4;
            int grow = row0 + row;
            float4 v = make_float4(0.f, 0.f, 0.f, 0.f);
            if (grow < M) v = *reinterpret_cast<const float4*>(&X[(size_t)grow * 256 + k0 + kq]);
            uint lo = (uint)f2bf(v.x) | ((uint)f2bf(v.y) << 16);
            uint hi = (uint)f2bf(v.z) | ((uint)f2bf(v.w) << 16);
            *reinterpret_cast<uint2*>(&Xs[row * G1_STRIDE + kq]) = make_uint2(lo, hi);
        }
        #pragma unroll
        for (int h = 0; h < 4; ++h) {
            int u = t + h * 256;
            int n = u >> 2;
            int seg = u & 3;
            uint4 wv = *reinterpret_cast<const uint4*>(&W1T[(size_t)n * 256 + k0 + seg * 8]);
            *reinterpret_cast<uint4*>(&Ws[n * G1_STRIDE + seg * 8]) = wv;
        }
        __syncthreads();
        bf16x8 wf[4], xf[4];
        #pragma unroll
        for (int j = 0; j < 4; ++j)
            wf[j] = *reinterpret_cast<const bf16x8*>(&Ws[(w * 64 + j * 16 + lr) * G1_STRIDE + lg * 8]);
        #pragma unroll
        for (int i = 0; i < 4; ++i)
            xf[i] = *reinterpret_cast<const bf16x8*>(&Xs[(i * 16 + lr) * G1_STRIDE + lg * 8]);
        #pragma unroll
        for (int j = 0; j < 4; ++j)
            #pragma unroll
            for (int i = 0; i < 4; ++i)
                acc[j][i] = __builtin_amdgcn_mfma_f32_16x16x32_bf16(wf[j], xf[i], acc[j][i], 0, 0, 0);
        __syncthreads();
    }

    // epilogue: scale by dinv[row], pack 4 f32 -> 4 fp8 e4m3 (one dword) per lane
    #pragma unroll
    for (int mi = 0; mi < 4; ++mi) {
        int grow = row0 + mi * 16 + lr;
        float dv = Dvs[mi * 16 + lr];
        bool ok = grow < M;
        #pragma unroll
        for (int nj = 0; nj < 4; ++nj) {
            f32x4 a = acc[nj][mi];
            int pk = __builtin_amdgcn_cvt_pk_fp8_f32(a[0] * dv, a[1] * dv, 0, false);
            pk     = __builtin_amdgcn_cvt_pk_fp8_f32(a[2] * dv, a[3] * dv, pk, true);
            if (ok) {
                int col = w * 64 + nj * 16 + lg * 4;
                *reinterpret_cast<uint*>(&H1[(size_t)grow * 256 + col]) = (uint)pk;
            }
        }
    }
}

// ---------- layer-1 aggregation (+b1, ELU) fused with GEMM2 (256->10) ----------
// one wave per node: 64 lanes x 4 features. UNIFORM edge index -> scalar ssrc
// loads + SGPR-base row loads (load-bearing, see R8). Unroll 16 for MLP.
__global__ __launch_bounds__(256) void agg1_gemm2_kernel(
    const uchar* __restrict__ H1, const int* __restrict__ offs, const int* __restrict__ ssrc,
    const float* __restrict__ dinv, const float* __restrict__ b1, const float* __restrict__ W2,
    float* __restrict__ H2, int NN) {
    int lane = threadIdx.x & 63;
    int node = blockIdx.x * 4 + (threadIdx.x >> 6);
    if (node >= NN) return;
    int beg = offs[node], end = offs[node + 1];
    int col = lane * 4;
    const uchar* H1c = H1 + col;
    f32x2 accL = (f32x2){0.f, 0.f};
    f32x2 accH = (f32x2){0.f, 0.f};
    int i = beg;
    for (; i + 15 < end; i += 16) {
        uint p0, p1, p2, p3, p4, p5, p6, p7, p8, p9, pa, pb, pc, pd, pe, pf;
        {
            int s0 = ssrc[i],      s1 = ssrc[i + 1],  s2 = ssrc[i + 2],  s3 = ssrc[i + 3];
            int s4 = ssrc[i + 4],  s5 = ssrc[i + 5],  s6 = ssrc[i + 6],  s7 = ssrc[i + 7];
            int s8 = ssrc[i + 8],  s9 = ssrc[i + 9],  sa = ssrc[i + 10], sb = ssrc[i + 11];
            int sc = ssrc[i + 12], sd = ssrc[i + 13], se = ssrc[i + 14], sf = ssrc[i + 15];
            p0 = *reinterpret_cast<const uint*>(H1c + (size_t)s0 * 256);
            p1 = *reinterpret_cast<const uint*>(H1c + (size_t)s1 * 256);
            p2 = *reinterpret_cast<const uint*>(H1c + (size_t)s2 * 256);
            p3 = *reinterpret_cast<const uint*>(H1c + (size_t)s3 * 256);
            p4 = *reinterpret_cast<const uint*>(H1c + (size_t)s4 * 256);
            p5 = *reinterpret_cast<const uint*>(H1c + (size_t)s5 * 256);
            p6 = *reinterpret_cast<const uint*>(H1c + (size_t)s6 * 256);
            p7 = *reinterpret_cast<const uint*>(H1c + (size_t)s7 * 256);
            p8 = *reinterpret_cast<const uint*>(H1c + (size_t)s8 * 256);
            p9 = *reinterpret_cast<const uint*>(H1c + (size_t)s9 * 256);
            pa = *reinterpret_cast<const uint*>(H1c + (size_t)sa * 256);
            pb = *reinterpret_cast<const uint*>(H1c + (size_t)sb * 256);
            pc = *reinterpret_cast<const uint*>(H1c + (size_t)sc * 256);
            pd = *reinterpret_cast<const uint*>(H1c + (size_t)sd * 256);
            pe = *reinterpret_cast<const uint*>(H1c + (size_t)se * 256);
            pf = *reinterpret_cast<const uint*>(H1c + (size_t)sf * 256);
        }
        accL += __builtin_amdgcn_cvt_pk_f32_fp8((int)p0, false);
        accH += __builtin_amdgcn_cvt_pk_f32_fp8((int)p0, true);
        accL += __builtin_amdgcn_cvt_pk_f32_fp8((int)p1, false);
        accH += __builtin_amdgcn_cvt_pk_f32_fp8((int)p1, true);
        accL += __builtin_amdgcn_cvt_pk_f32_fp8((int)p2, false);
        accH += __builtin_amdgcn_cvt_pk_f32_fp8((int)p2, true);
        accL += __builtin_amdgcn_cvt_pk_f32_fp8((int)p3, false);
        accH += __builtin_amdgcn_cvt_pk_f32_fp8((int)p3, true);
        accL += __builtin_amdgcn_cvt_pk_f32_fp8((int)p4, false);
        accH += __builtin_amdgcn_cvt_pk_f32_fp8((int)p4, true);
        accL += __builtin_amdgcn_cvt_pk_f32_fp8((int)p5, false);
        accH += __builtin_amdgcn_cvt_pk_f32_fp8((int)p5, true);
        accL += __builtin_amdgcn_cvt_pk_f32_fp8((int)p6, false);
        accH += __builtin_amdgcn_cvt_pk_f32_fp8((int)p6, true);
        accL += __builtin_amdgcn_cvt_pk_f32_fp8((int)p7, false);
        accH += __builtin_amdgcn_cvt_pk_f32_fp8((int)p7, true);
        accL += __builtin_amdgcn_cvt_pk_f32_fp8((int)p8, false);
        accH += __builtin_amdgcn_cvt_pk_f32_fp8((int)p8, true);
        accL += __builtin_amdgcn_cvt_pk_f32_fp8((int)p9, false);
        accH += __builtin_amdgcn_cvt_pk_f32_fp8((int)p9, true);
        accL += __builtin_amdgcn_cvt_pk_f32_fp8((int)pa, false);
        accH += __builtin_amdgcn_cvt_pk_f32_fp8((int)pa, true);
        accL += __builtin_amdgcn_cvt_pk_f32_fp8((int)pb, false);
        accH += __builtin_amdgcn_cvt_pk_f32_fp8((int)pb, true);
        accL += __builtin_amdgcn_cvt_pk_f32_fp8((int)pc, false);
        accH += __builtin_amdgcn_cvt_pk_f32_fp8((int)pc, true);
        accL += __builtin_amdgcn_cvt_pk_f32_fp8((int)pd, false);
        accH += __builtin_amdgcn_cvt_pk_f32_fp8((int)pd, true);
        accL += __builtin_amdgcn_cvt_pk_f32_fp8((int)pe, false);
        accH += __builtin_amdgcn_cvt_pk_f32_fp8((int)pe, true);
        accL += __builtin_amdgcn_cvt_pk_f32_fp8((int)pf, false);
        accH += __builtin_amdgcn_cvt_pk_f32_fp8((int)pf, true);
    }
    for (; i + 3 < end; i += 4) {
        int s0 = ssrc[i], s1 = ssrc[i + 1], s2 = ssrc[i + 2], s3 = ssrc[i + 3];
        uint p0 = *reinterpret_cast<const uint*>(H1c + (size_t)s0 * 256);
        uint p1 = *reinterpret_cast<const uint*>(H1c + (size_t)s1 * 256);
        uint p2 = *reinterpret_cast<const uint*>(H1c + (size_t)s2 * 256);
        uint p3 = *reinterpret_cast<const uint*>(H1c + (size_t)s3 * 256);
        accL += __builtin_amdgcn_cvt_pk_f32_fp8((int)p0, false);
        accH += __builtin_amdgcn_cvt_pk_f32_fp8((int)p0, true);
        accL += __builtin_amdgcn_cvt_pk_f32_fp8((int)p1, false);
        accH += __builtin_amdgcn_cvt_pk_f32_fp8((int)p1, true);
        accL += __builtin_amdgcn_cvt_pk_f32_fp8((int)p2, false);
        accH += __builtin_amdgcn_cvt_pk_f32_fp8((int)p2, true);
        accL += __builtin_amdgcn_cvt_pk_f32_fp8((int)p3, false);
        accH += __builtin_amdgcn_cvt_pk_f32_fp8((int)p3, true);
    }
    for (; i < end; ++i) {
        int s = ssrc[i];
        uint p = *reinterpret_cast<const uint*>(H1c + (size_t)s * 256);
        accL += __builtin_amdgcn_cvt_pk_f32_fp8((int)p, false);
        accH += __builtin_amdgcn_cvt_pk_f32_fp8((int)p, true);
    }
    {   // self loop (row pre-scaled by dinv[node])
        uint p = *reinterpret_cast<const uint*>(H1c + (size_t)node * 256);
        accL += __builtin_amdgcn_cvt_pk_f32_fp8((int)p, false);
        accH += __builtin_amdgcn_cvt_pk_f32_fp8((int)p, true);
    }
    float dn = dinv[node];
    float a0 = elu(fmaf(accL.x, dn, b1[col + 0]));
    float a1 = elu(fmaf(accL.y, dn, b1[col + 1]));
    float a2 = elu(fmaf(accH.x, dn, b1[col + 2]));
    float a3 = elu(fmaf(accH.y, dn, b1[col + 3]));
    float hv = 0.f;
    #pragma unroll
    for (int c = 0; c < 10; ++c) {
        float p = a0 * W2[(col + 0) * 10 + c]
                + a1 * W2[(col + 1) * 10 + c]
                + a2 * W2[(col + 2) * 10 + c]
                + a3 * W2[(col + 3) * 10 + c];
        #pragma unroll
        for (int m = 1; m < 64; m <<= 1) p += __shfl_xor(p, m, 64);
        if (lane == c) hv = p;
    }
    if (lane < 10) H2[(size_t)node * H2S + lane] = dn * hv;   // fold dinv[node]
}

// ---------- layer-2 aggregation (+b2, ELU) -> per-node activations ----------
__global__ __launch_bounds__(256) void agg2_elu_kernel(
    const float* __restrict__ H2, const int* __restrict__ offs, const int* __restrict__ ssrc,
    const float* __restrict__ dinv, const float* __restrict__ b2,
    float* __restrict__ H2act, int NN) {
    int t = threadIdx.x;
    int node = blockIdx.x * 8 + (t >> 5);
    if (node >= NN) return;
    int sub = t & 31;
    int c = sub & 15;
    int e2 = sub >> 4;
    int beg = offs[node], end = offs[node + 1];
    float acc = 0.f;
    int i = beg + e2;
    for (; i + 14 < end; i += 16) {   // 8 edges per thread per iter
        int s0 = ssrc[i],      s1 = ssrc[i + 2],  s2 = ssrc[i + 4],  s3 = ssrc[i + 6];
        int s4 = ssrc[i + 8],  s5 = ssrc[i + 10], s6 = ssrc[i + 12], s7 = ssrc[i + 14];
        float h0 = H2[(size_t)s0 * H2S + c];
        float h1 = H2[(size_t)s1 * H2S + c];
        float h2 = H2[(size_t)s2 * H2S + c];
        float h3 = H2[(size_t)s3 * H2S + c];
        float h4 = H2[(size_t)s4 * H2S + c];
        float h5 = H2[(size_t)s5 * H2S + c];
        float h6 = H2[(size_t)s6 * H2S + c];
        float h7 = H2[(size_t)s7 * H2S + c];
        acc += ((h0 + h1) + (h2 + h3)) + ((h4 + h5) + (h6 + h7));
    }
    for (; i + 6 < end; i += 8) {
        int s0 = ssrc[i], s1 = ssrc[i + 2], s2 = ssrc[i + 4], s3 = ssrc[i + 6];
        float h0 = H2[(size_t)s0 * H2S + c];
        float h1 = H2[(size_t)s1 * H2S + c];
        float h2 = H2[(size_t)s2 * H2S + c];
        float h3 = H2[(size_t)s3 * H2S + c];
        acc += (h0 + h1) + (h2 + h3);
    }
    for (; i < end; i += 2) acc += H2[(size_t)ssrc[i] * H2S + c];
    if (e2 == 0) acc += H2[(size_t)node * H2S + c];   // self loop (pre-scaled)
    acc += __shfl_xor(acc, 16, 64);
    if (sub < 10) {
        float dn = dinv[node];
        H2act[(size_t)node * 10 + c] = elu(fmaf(dn, acc, b2[c]));
    }
}

// ---------- per-graph mean pool + log_softmax (binary search inline) ----------
__global__ __launch_bounds__(320) void pool_final_kernel(
    const float* __restrict__ H2act, const int* __restrict__ batch, int NN,
    float* __restrict__ out, int NG) {
    __shared__ float red[32][10];
    __shared__ float m[10];
    __shared__ float s_lse;
    int g = blockIdx.x;
    int t = threadIdx.x;
    int lo = 0, hi = NN;
    while (lo < hi) { int mid = (lo + hi) >> 1; if (batch[mid] < g) lo = mid + 1; else hi = mid; }
    int lo2 = lo, hi2 = NN;
    while (lo2 < hi2) { int mid = (lo2 + hi2) >> 1; if (batch[mid] < g + 1) lo2 = mid + 1; else hi2 = mid; }
    int grp = t / 10;
    int c = t - grp * 10;
    float acc = 0.f;
    if (grp < 32) {
        for (int n = lo + grp; n < lo2; n += 32) acc += H2act[(size_t)n * 10 + c];
        red[grp][c] = acc;
    }
    __syncthreads();
    if (t < 10) {
        float s = 0.f;
        #pragma unroll
        for (int j = 0; j < 32; ++j) s += red[j][t];
        m[t] = s / fmaxf((float)(lo2 - lo), 1.0f);
    }
    __syncthreads();
    if (t == 0) {
        float mx = -1e30f;
        for (int c2 = 0; c2 < 10; ++c2) mx = fmaxf(mx, m[c2]);
        float s = 0.f;
        for (int c2 = 0; c2 < 10; ++c2) s += expf(m[c2] - mx);
        s_lse = logf(s) + mx;
    }
    __syncthreads();
    if (t < 10) out[g * 10 + t] = m[t] - s_lse;
}

extern "C" void kernel_launch(void* const* d_in, const int* in_sizes, int n_in,
                              void* d_out, int out_size, void* d_ws, size_t ws_size,
                              hipStream_t stream) {
    const float* x     = (const float*)d_in[0];
    const int*   eidx  = (const int*)d_in[1];
    const int*   batch = (const int*)d_in[2];
    const float* W1    = (const float*)d_in[3];
    const float* b1    = (const float*)d_in[4];
    const float* W2    = (const float*)d_in[5];
    const float* b2    = (const float*)d_in[6];

    int NN = in_sizes[0] / 256;     // 50000
    int E  = in_sizes[1] / 2;       // 1600000
    int NG = out_size / 10;         // 64
    const int* src = eidx;
    const int* dst = eidx + E;

    char* ws = (char*)d_ws;
    size_t off = 0;
    auto alloc = [&](size_t bytes) -> void* {
        void* p = ws + off;
        off += (bytes + 255) & ~((size_t)255);
        return p;
    };
    int*    cnt      = (int*)alloc((size_t)NN * 4);
    int*    offs     = (int*)alloc((size_t)(NN + 1) * 4);
    int*    cursor   = (int*)alloc((size_t)NN * 4);
    int*    partials = (int*)alloc(4096 * 4);
    int*    pscan    = (int*)alloc(4096 * 4);
    float*  dinv     = (float*)alloc((size_t)NN * 4);
    ushort* W1T      = (ushort*)alloc((size_t)256 * 256 * 2);
    int*    ssrc     = (int*)alloc((size_t)E * 4);
    uchar*  H1       = (uchar*)alloc((size_t)NN * 256);
    float*  H2       = (float*)alloc((size_t)NN * H2S * 4);
    float*  H2act    = (float*)alloc((size_t)NN * 10 * 4);

    hipMemsetAsync(cnt, 0, (size_t)NN * 4, stream);

    int nb = (NN + 255) / 256;      // 196
    count_kernel  <<<2048, 256, 0, stream>>>(dst, E, cnt, NN);
    scan1_kernel  <<<nb, 256, 0, stream>>>(cnt, NN, partials);
    scan2_kernel  <<<1, 256, 0, stream>>>(partials, nb, pscan);
    scan3_kernel  <<<nb, 256, 0, stream>>>(cnt, NN, pscan, offs, cursor, dinv);
    scatter_kernel<<<2048, 256, 0, stream>>>(src, dst, E, cursor, ssrc, NN);
    wtrans_kernel <<<16, 256, 0, stream>>>(W1, W1T);
    gemm1_mfma_kernel<<<(NN + 63) / 64, 256, 0, stream>>>(x, W1T, dinv, H1, NN);
    agg1_gemm2_kernel<<<(NN + 3) / 4, 256, 0, stream>>>(H1, offs, ssrc, dinv, b1, W2, H2, NN);
    agg2_elu_kernel  <<<(NN + 7) / 8, 256, 0, stream>>>(H2, offs, ssrc, dinv, b2, H2act, NN);
    pool_final_kernel<<<NG, 320, 0, stream>>>(H2act, batch, NN, (float*)d_out, NG);
}